// Round 19
// baseline (283.097 us; speedup 1.0000x reference)
//
#include <hip/hip_runtime.h>
#include <math.h>

#define B_   2
#define S_   2048
#define D_   1024
#define H_   16
#define K_   21
#define HD_  64
#define D3_  3072
#define D2_  2048
#define REL_ 4095  // 2S-1
#define LOG2E 1.44269504f

typedef __attribute__((ext_vector_type(8))) short bf16x8;
typedef __attribute__((ext_vector_type(8))) unsigned short u16x8;
typedef __attribute__((ext_vector_type(4))) float f32x4;

#define MFMA16(a, b, c) __builtin_amdgcn_mfma_f32_16x16x32_bf16((a), (b), (c), 0, 0, 0)

__device__ __forceinline__ unsigned short f2bf(float f) {
    union { float f; unsigned u; } v; v.f = f;
    return (unsigned short)((v.u + 0x7fffu + ((v.u >> 16) & 1u)) >> 16);
}
__device__ __forceinline__ float bf2f(unsigned short h) {
    union { unsigned u; float f; } v; v.u = ((unsigned)h) << 16;
    return v.f;
}
__device__ __forceinline__ float asf(unsigned u) {
    union { unsigned u; float f; } v; v.u = u; return v.f;
}
// raw HW exp2: D = 2^S0 (what __expf uses internally, minus the mul)
__device__ __forceinline__ float fexp2(float x) {
    float r;
    asm("v_exp_f32 %0, %1" : "=v"(r) : "v"(x));
    return r;
}
// HW pair convert: dst[15:0]=bf16(a) (RTNE), dst[31:16]=bf16(b)
__device__ __forceinline__ unsigned cvtpk(float a, float b) {
    unsigned r;
    asm("v_cvt_pk_bf16_f32 %0, %1, %2" : "=v"(r) : "v"(a), "v"(b));
    return r;
}
// split 8 f32 -> hi bf16x8 + lo bf16x8 (bit-identical to f2bf-based split)
#define SPLIT8(f, ph, pl)                                                      \
    {                                                                          \
        _Pragma("unroll")                                                      \
        for (int _t = 0; _t < 4; ++_t) ph.u[_t] = cvtpk(f[2*_t], f[2*_t+1]);   \
        _Pragma("unroll")                                                      \
        for (int _t = 0; _t < 4; ++_t) {                                       \
            float _h0 = asf(ph.u[_t] << 16);                                   \
            float _h1 = asf(ph.u[_t] & 0xffff0000u);                           \
            pl.u[_t] = cvtpk(f[2*_t] - _h0, f[2*_t+1] - _h1);                  \
        }                                                                      \
    }

// async global->LDS, 16B per lane; LDS dest = wave-uniform base + lane*16
__device__ __forceinline__ void gload16(const void* g, void* l) {
    __builtin_amdgcn_global_load_lds(
        (const __attribute__((address_space(1))) unsigned int*)g,
        (__attribute__((address_space(3))) unsigned int*)l, 16, 0, 0);
}

// ---------------- TISA relative-position bias table (pre-scaled by log2e) ----
__global__ void tisa_bias_kernel(const float* __restrict__ amp,
                                 const float* __restrict__ shp,
                                 const float* __restrict__ off,
                                 float* __restrict__ bias_rel) {
    int idx = blockIdx.x * blockDim.x + threadIdx.x;
    if (idx >= H_ * REL_) return;
    int h = idx / REL_;
    int r = idx - h * REL_;
    float rel = (float)(r - (S_ - 1));
    float acc = 0.f;
    #pragma unroll
    for (int k = 0; k < K_; ++k) {
        float d = rel - off[h * K_ + k];
        acc = fmaf(amp[h * K_ + k], expf(-fabsf(shp[h * K_ + k]) * d * d), acc);
    }
    bias_rel[idx] = acc * LOG2E;   // attention works in log2 domain
}

// ---------------- x -> chunk format (no transpose) ----------------
// out[row][kc][64] u16: hi[32]|lo[32], row stride 2048 u16 (4096 B)
__global__ __launch_bounds__(256) void convert_x_kernel(
    const float* __restrict__ in, unsigned short* __restrict__ out)
{
    const int t   = blockIdx.x * 256 + threadIdx.x;  // 0..524287
    const int row = t >> 7;
    const int c8  = (t & 127) * 8;
    const float* src = in + (size_t)row * D_ + c8;
    float v[8];
    *(float4*)&v[0] = *(const float4*)src;
    *(float4*)&v[4] = *(const float4*)(src + 4);
    unsigned short hi[8], lo[8];
    #pragma unroll
    for (int i = 0; i < 8; ++i) {
        hi[i] = f2bf(v[i]);
        lo[i] = f2bf(v[i] - bf2f(hi[i]));
    }
    const int kc = c8 >> 5;
    const int j0 = c8 & 31;
    unsigned short* op = out + (size_t)row * 2048 + kc * 64;
    *(u16x8*)&op[j0]      = *(u16x8*)&hi[0];
    *(u16x8*)&op[32 + j0] = *(u16x8*)&lo[0];
}

// ---------------- weight transpose + bf16 split (chunk format) ----------------
// in: Kd x N fp32 row-major.  out: [Ndest][Kd/32][64] ushort, chunk = hi[32]|lo[32].
// PERM: dest col = 2*src (src<1024) or 2*(src-1024)+1 (gate interleave).
template<bool PERM>
__global__ __launch_bounds__(256) void convert_wT_kernel(
    const float* __restrict__ in, unsigned short* __restrict__ out, int Kd, int N)
{
    __shared__ float t[64][65];
    const int tid = threadIdx.x;
    const int k0 = blockIdx.y * 64;
    const int n0 = blockIdx.x * 64;
    {
        const int r  = tid >> 2;
        const int cq = (tid & 3) * 16;
        #pragma unroll
        for (int e = 0; e < 4; ++e) {
            float4 v = *(const float4*)&in[(size_t)(k0 + r) * N + n0 + cq + 4 * e];
            t[r][cq + 4 * e + 0] = v.x;
            t[r][cq + 4 * e + 1] = v.y;
            t[r][cq + 4 * e + 2] = v.z;
            t[r][cq + 4 * e + 3] = v.w;
        }
    }
    __syncthreads();
    {
        const int n  = tid >> 2;
        const int ks = (tid & 3) * 16;
        const int nkc = Kd >> 5;
        unsigned short hi[16], lo[16];
        #pragma unroll
        for (int i = 0; i < 16; ++i) {
            float v = t[ks + i][n];
            hi[i] = f2bf(v);
            lo[i] = f2bf(v - bf2f(hi[i]));
        }
        const int kg = k0 + ks;
        const int kc = kg >> 5;
        const int j0 = kg & 31;
        const int nsrc = n0 + n;
        const int dc = PERM ? ((nsrc < 1024) ? 2 * nsrc : 2 * (nsrc - 1024) + 1) : nsrc;
        unsigned short* op = out + (size_t)dc * (nkc * 64) + kc * 64;
        *(u16x8*)&op[j0]          = *(u16x8*)&hi[0];
        *(u16x8*)&op[j0 + 8]      = *(u16x8*)&hi[8];
        *(u16x8*)&op[32 + j0]     = *(u16x8*)&lo[0];
        *(u16x8*)&op[32 + j0 + 8] = *(u16x8*)&lo[8];
    }
}

// ---------------- bf16x3 split-precision MFMA GEMM, 128x128 tile ----------
// (round-18 validated version, unchanged)
template<int EPI>
__global__ __launch_bounds__(256) void gemm_split_kernel(
    const void* Ap, const unsigned short* __restrict__ Bt,
    const float* __restrict__ bias, float* C,
    int N, int Kd, int lda, int ldc)
{
    __shared__ unsigned short Al[2][128 * 64];  // 2 x 16 KB
    __shared__ unsigned short Bl[2][128 * 64];  // 2 x 16 KB
    const int tid  = threadIdx.x;
    const int w    = tid >> 6;
    const int lane = tid & 63;
    const int c    = lane & 15;
    const int g    = lane >> 4;
    const int m0   = blockIdx.y * 128;
    const int n0   = blockIdx.x * 128;
    const int wrow = (w >> 1) * 64;
    const int wcol = (w & 1) * 64;
    const int nkc  = Kd >> 5;

    f32x4 acc[4][4];
    #pragma unroll
    for (int i = 0; i < 4; ++i)
        #pragma unroll
        for (int j = 0; j < 4; ++j) acc[i][j] = (f32x4){0.f, 0.f, 0.f, 0.f};

    const int srowB  = w * 8 + (lane >> 3);
    const int sslotB = lane & 7;

#define STAGE_AB(buf, kcv)                                                    \
    {                                                                         \
        _Pragma("unroll")                                                     \
        for (int i = 0; i < 4; ++i) {                                         \
            const int row = w * 32 + i * 8 + (lane >> 3);                     \
            const char* src = (const char*)Ap + (size_t)(m0 + row) * lda      \
                            + (kcv) * 128 + (((lane & 7) ^ (row & 7)) << 4);  \
            gload16(src, (char*)Al[buf] + w * 4096 + i * 1024);               \
        }                                                                     \
        _Pragma("unroll")                                                     \
        for (int i = 0; i < 4; ++i) {                                         \
            const int n = i * 32 + srowB;                                     \
            const unsigned short* src = Bt                                    \
                + ((size_t)(n0 + n) * nkc + (kcv)) * 64                       \
                + ((sslotB ^ (n & 7)) << 3);                                  \
            gload16(src, (char*)Bl[buf] + i * 4096 + w * 1024);               \
        }                                                                     \
    }

    STAGE_AB(0, 0);   // 8 loads in flight for buf0
    int cur = 0;

    for (int kc = 0; kc < nkc; ++kc) {
        if (kc + 1 < nkc) {
            STAGE_AB(cur ^ 1, kc + 1);  // +8 loads; 16 in flight
            asm volatile("s_waitcnt vmcnt(8)" ::: "memory");  // prev 8 done
        } else {
            asm volatile("s_waitcnt vmcnt(0)" ::: "memory");
        }
        __builtin_amdgcn_s_barrier();       // publish all waves' buf[cur]
        __builtin_amdgcn_sched_barrier(0);

        bf16x8 ah[4], al[4], bh[4], bl[4];
        #pragma unroll
        for (int f = 0; f < 4; ++f) {
            const int m = wrow + f * 16 + c;
            const char* rp = (const char*)Al[cur] + m * 128;
            ah[f] = *(const bf16x8*)(rp + (((g + 0) ^ (m & 7)) << 4));
            al[f] = *(const bf16x8*)(rp + (((g + 4) ^ (m & 7)) << 4));
            const int n = wcol + f * 16 + c;
            const char* rq = (const char*)Bl[cur] + n * 128;
            bh[f] = *(const bf16x8*)(rq + (((g + 0) ^ (n & 7)) << 4));
            bl[f] = *(const bf16x8*)(rq + (((g + 4) ^ (n & 7)) << 4));
        }
        #pragma unroll
        for (int mf = 0; mf < 4; ++mf)
            #pragma unroll
            for (int nf = 0; nf < 4; ++nf) {
                acc[mf][nf] = MFMA16(ah[mf], bh[nf], acc[mf][nf]);
                acc[mf][nf] = MFMA16(al[mf], bh[nf], acc[mf][nf]);
                acc[mf][nf] = MFMA16(ah[mf], bl[nf], acc[mf][nf]);
            }
        // WAR: all waves done reading buf[cur] before next iter stages into it
        asm volatile("s_waitcnt lgkmcnt(0)" ::: "memory");
        __builtin_amdgcn_s_barrier();
        cur ^= 1;
    }
#undef STAGE_AB

    // ---------------- epilogues ----------------
    if (EPI == 1) {
        if (n0 < 1024) {  // K hi/lo planes into proj row bytes [4096,8192)
            #pragma unroll
            for (int mf = 0; mf < 4; ++mf)
                #pragma unroll
                for (int r = 0; r < 4; ++r) {
                    const int row = m0 + wrow + mf * 16 + g * 4 + r;
                    char* rowB = (char*)C + (size_t)row * 12288;
                    #pragma unroll
                    for (int nf = 0; nf < 4; ++nf) {
                        const int col = n0 + wcol + nf * 16 + c;
                        const float val = acc[mf][nf][r];
                        const unsigned short hi = f2bf(val);
                        *(unsigned short*)(rowB + 4096 + 2 * col) = hi;
                        *(unsigned short*)(rowB + 6144 + 2 * col) = f2bf(val - bf2f(hi));
                    }
                }
        } else if (n0 < 2048) {  // V^T planes: i=b*1024+d -> rows 2i/2i+1 bytes [0,4096)
            #pragma unroll
            for (int mf = 0; mf < 4; ++mf) {
                const int row0 = m0 + wrow + mf * 16 + g * 4;
                const int s2 = (row0 & 2047) * 2;
                const size_t ibase = (size_t)(row0 >> 11) * 1024;
                #pragma unroll
                for (int nf = 0; nf < 4; ++nf) {
                    const int d = n0 - 1024 + wcol + nf * 16 + c;
                    ushort4 hv, lv;
                    {
                        float v0 = acc[mf][nf][0], v1 = acc[mf][nf][1];
                        float v2 = acc[mf][nf][2], v3 = acc[mf][nf][3];
                        hv.x = f2bf(v0); lv.x = f2bf(v0 - bf2f(hv.x));
                        hv.y = f2bf(v1); lv.y = f2bf(v1 - bf2f(hv.y));
                        hv.z = f2bf(v2); lv.z = f2bf(v2 - bf2f(hv.z));
                        hv.w = f2bf(v3); lv.w = f2bf(v3 - bf2f(hv.w));
                    }
                    char* base = (char*)C + (ibase + d) * (size_t)24576 + s2;
                    *(ushort4*)base           = hv;
                    *(ushort4*)(base + 12288) = lv;
                }
            }
        } else {  // Q fp32
            #pragma unroll
            for (int mf = 0; mf < 4; ++mf)
                #pragma unroll
                for (int r = 0; r < 4; ++r) {
                    const int row = m0 + wrow + mf * 16 + g * 4 + r;
                    float* cp = &C[(size_t)row * ldc + n0 + wcol + c];
                    #pragma unroll
                    for (int nf = 0; nf < 4; ++nf)
                        cp[nf * 16] = acc[mf][nf][r];
                }
        }
    } else {  // EPI == 2: fused gate. even col jc=2t holds a_t, odd holds g_t.
        float bgs[4];
        #pragma unroll
        for (int nf = 0; nf < 4; ++nf) {
            const int jc = n0 + wcol + nf * 16 + c;
            bgs[nf] = bias[(jc & 1) ? (1024 + (jc >> 1)) : (jc >> 1)];
        }
        #pragma unroll
        for (int mf = 0; mf < 4; ++mf)
            #pragma unroll
            for (int r = 0; r < 4; ++r) {
                const int row = m0 + wrow + mf * 16 + g * 4 + r;
                #pragma unroll
                for (int nf = 0; nf < 4; ++nf) {
                    const int jc = n0 + wcol + nf * 16 + c;
                    const float val = acc[mf][nf][r] + bgs[nf];
                    const float part = __shfl_xor(val, 1);
                    if (!(c & 1))
                        C[(size_t)row * ldc + (jc >> 1)] = val / (1.f + __expf(-part));
                }
            }
    }
}

// ---------------- MFMA flash attention: 4 waves x 32 q-rows each ----------
// LDS-BW optimization: each wave owns TWO 16-q sets (qs=0,1), so every K and
// V fragment read from LDS feeds 6 MFMA instead of 3 (427 B/MFMA vs 768).
// K planes in proj rows (bytes [4096,6144)=Khi, [6144,8192)=Klo per row);
// V^T planes: plane-row i=b*1024+d at proj rows 2i (hi) / 2i+1 (lo);
// Q fp32 at bytes [8192,12288); O chunks overwrite Q bytes.
// Staging via global_load_lds (source-swizzled, linear LDS dest).
// Grid: 512 blocks 1-D, XCD-decoded (16 q-blocks of one (h,b) -> one XCD).
__global__ __launch_bounds__(256) void attn_mfma_kernel(
    const float* projf, char* projB, const float* __restrict__ bias_rel)
{
    __shared__ unsigned short KHI[4096], KLO[4096], VHI[4096], VLO[4096];  // 8 KB each
    __shared__ unsigned short PHI[4096], PLO[4096];  // 128q x 32k slice, 8 KB each
    __shared__ float bias_s[192];

    const int tid  = threadIdx.x;
    const int w    = tid >> 6;    // 0..3
    const int lane = tid & 63;
    const int c    = lane & 15;
    const int g    = lane >> 4;
    // XCD-aware decode: 16 q-blocks of one (h,b) panel land on one XCD
    const int bid  = blockIdx.x;
    const int xcd  = bid & 7;
    const int slot = bid >> 3;            // 0..63
    const int qt   = slot & 15;
    const int p    = (slot >> 4) * 8 + xcd;  // 0..31
    const int h    = p >> 1;
    const int b    = p & 1;
    const int qbase = qt * 128;
    const size_t rowbase = (size_t)b * S_;

    // Q fragments, 2 q-sets: q row = 32w + 16*qs + c
    bf16x8 Qhi[2][2], Qlo[2][2];
    #pragma unroll
    for (int qs = 0; qs < 2; ++qs) {
        const float* qp = projf + (rowbase + qbase + 32 * w + 16 * qs + c) * D3_
                        + 2 * D_ + h * HD_;
        #pragma unroll
        for (int ck = 0; ck < 2; ++ck) {
            float q8[8];
            *(float4*)&q8[0] = *(const float4*)(qp + ck * 32 + g * 8);
            *(float4*)&q8[4] = *(const float4*)(qp + ck * 32 + g * 8 + 4);
            union { unsigned u[4]; bf16x8 v; } ph, pl;
            const float* f = q8;
            SPLIT8(f, ph, pl);
            Qhi[qs][ck] = ph.v;
            Qlo[qs][ck] = pl.v;
        }
    }

    f32x4 o_acc[2][4];
    #pragma unroll
    for (int qs = 0; qs < 2; ++qs)
        #pragma unroll
        for (int n = 0; n < 4; ++n) o_acc[qs][n] = (f32x4){0.f, 0.f, 0.f, 0.f};
    float m_run[2] = {-INFINITY, -INFINITY};
    float l_run[2] = {0.f, 0.f};

    // staging geometry: wave w stages rows [16w,16w+16) of all 4 buffers;
    // row = 16w + i*8 + (lane>>3), slot = lane&7; row&7 = lane>>3 (w,i free)
    const int gsl = (lane & 7) ^ (lane >> 3);
    float breg = 0.f;
    if (tid < 191) breg = bias_rel[h * REL_ - qbase + 1920 + tid];

    for (int kt = 0; kt < S_ / 64; ++kt) {
        const int kbase = kt * 64;
        __syncthreads();  // previous tile's LDS reads complete
        #pragma unroll
        for (int i = 0; i < 2; ++i) {
            const int row = 16 * w + i * 8 + (lane >> 3);
            const char* ks = projB + (rowbase + kbase + row) * (size_t)12288
                           + 4096 + h * 128 + gsl * 16;
            gload16(ks,        (char*)KHI + w * 2048 + i * 1024);
            gload16(ks + 2048, (char*)KLO + w * 2048 + i * 1024);
            const char* vs = projB + (size_t)(b * 1024 + h * HD_ + row) * 24576
                           + (size_t)kbase * 2 + gsl * 16;
            gload16(vs,         (char*)VHI + w * 2048 + i * 1024);
            gload16(vs + 12288, (char*)VLO + w * 2048 + i * 1024);
        }
        if (tid < 191) {
            bias_s[tid] = breg;
            if (kt + 1 < S_ / 64)
                breg = bias_rel[h * REL_ + (kt + 1) * 64 - qbase + 1920 + tid];
        }
        __syncthreads();  // staging visible

        // ---- S^T = K Q (bf16x3), both q-sets share each K fragment ----
        f32x4 sf[2][4];
        __builtin_amdgcn_s_setprio(1);
        #pragma unroll
        for (int f = 0; f < 4; ++f) {
            f32x4 a0 = (f32x4){0.f, 0.f, 0.f, 0.f};
            f32x4 a1 = (f32x4){0.f, 0.f, 0.f, 0.f};
            const int krow = f * 16 + c;
            const unsigned short* kbp = KHI + krow * 64;
            const unsigned short* klp = KLO + krow * 64;
            #pragma unroll
            for (int ck = 0; ck < 2; ++ck) {
                const int s = ((ck * 4 + g) ^ (krow & 7)) * 8;
                bf16x8 kh  = *(const bf16x8*)(kbp + s);
                bf16x8 kl8 = *(const bf16x8*)(klp + s);
                a0 = MFMA16(kh, Qhi[0][ck], a0);
                a1 = MFMA16(kh, Qhi[1][ck], a1);
                a0 = MFMA16(kl8, Qhi[0][ck], a0);
                a1 = MFMA16(kl8, Qhi[1][ck], a1);
                a0 = MFMA16(kh, Qlo[0][ck], a0);
                a1 = MFMA16(kh, Qlo[1][ck], a1);
            }
            sf[0][f] = a0;
            sf[1][f] = a1;
        }
        __builtin_amdgcn_s_setprio(0);

        // ---- per q-set: bias + lane-local online softmax (log2 domain) ----
        #pragma unroll
        for (int qs = 0; qs < 2; ++qs) {
            const int qe = 32 * w + 16 * qs + c;
            #pragma unroll
            for (int f = 0; f < 4; ++f) {
                const int tb = 16 * f + 4 * g - qe + 127;
                #pragma unroll
                for (int r = 0; r < 4; ++r)
                    sf[qs][f][r] = fmaf(sf[qs][f][r], 0.125f * LOG2E, bias_s[tb + r]);
            }
            float pm[4];
            #pragma unroll
            for (int f = 0; f < 4; ++f)
                pm[f] = fmaxf(fmaxf(sf[qs][f][0], sf[qs][f][1]),
                              fmaxf(sf[qs][f][2], sf[qs][f][3]));
            float mt = fmaxf(fmaxf(pm[0], pm[1]), fmaxf(pm[2], pm[3]));
            mt = fmaxf(mt, __shfl_xor(mt, 16));
            mt = fmaxf(mt, __shfl_xor(mt, 32));
            if (!__all(mt <= m_run[qs] + 11.5415603f)) {
                const float mn = fmaxf(m_run[qs], mt);
                const float sc = fexp2(m_run[qs] - mn);
                l_run[qs] *= sc;
                m_run[qs] = mn;
                #pragma unroll
                for (int r = 0; r < 4; ++r) {
                    const float scr = __shfl(sc, 20 * g + r);
                    #pragma unroll
                    for (int n = 0; n < 4; ++n) o_acc[qs][n][r] *= scr;
                }
            }
            float ps[4];
            #pragma unroll
            for (int f = 0; f < 4; ++f) {
                #pragma unroll
                for (int r = 0; r < 4; ++r)
                    sf[qs][f][r] = fexp2(sf[qs][f][r] - m_run[qs]);
                ps[f] = (sf[qs][f][0] + sf[qs][f][1]) + (sf[qs][f][2] + sf[qs][f][3]);
            }
            float rs = (ps[0] + ps[1]) + (ps[2] + ps[3]);
            rs += __shfl_xor(rs, 16);
            rs += __shfl_xor(rs, 32);
            l_run[qs] += rs;
        }

        // ---- O += P V per 32-k slice; V fragments shared by both q-sets ----
        #pragma unroll
        for (int ck = 0; ck < 2; ++ck) {
            #pragma unroll
            for (int qs = 0; qs < 2; ++qs) {
                const int qe  = 32 * w + 16 * qs + c;
                const int psw = (qe & 3) ^ ((qe >> 2) & 1);
                #pragma unroll
                for (int f2 = 0; f2 < 2; ++f2) {
                    const int f = 2 * ck + f2;
                    const unsigned uh0 = cvtpk(sf[qs][f][0], sf[qs][f][1]);
                    const unsigned uh1 = cvtpk(sf[qs][f][2], sf[qs][f][3]);
                    const float r0 = sf[qs][f][0] - asf(uh0 << 16);
                    const float r1 = sf[qs][f][1] - asf(uh0 & 0xffff0000u);
                    const float r2 = sf[qs][f][2] - asf(uh1 << 16);
                    const float r3 = sf[qs][f][3] - asf(uh1 & 0xffff0000u);
                    const unsigned ul0 = cvtpk(r0, r1);
                    const unsigned ul1 = cvtpk(r2, r3);
                    const int byte = qe * 64
                        + ((((2 * f2 + (g >> 1)) ^ psw) << 4) + ((g & 1) << 3));
                    uint2 vh2; vh2.x = uh0; vh2.y = uh1;
                    uint2 vl2; vl2.x = ul0; vl2.y = ul1;
                    *(uint2*)((char*)PHI + byte) = vh2;
                    *(uint2*)((char*)PLO + byte) = vl2;
                }
            }
            asm volatile("s_waitcnt lgkmcnt(0)" ::: "memory");
            bf16x8 pah[2], pal[2];
            #pragma unroll
            for (int qs = 0; qs < 2; ++qs) {
                const int qe  = 32 * w + 16 * qs + c;
                const int psw = (qe & 3) ^ ((qe >> 2) & 1);
                const int rbyte = qe * 64 + ((g ^ psw) << 4);
                pah[qs] = *(const bf16x8*)((char*)PHI + rbyte);
                pal[qs] = *(const bf16x8*)((char*)PLO + rbyte);
            }
            __builtin_amdgcn_s_setprio(1);
            #pragma unroll
            for (int n = 0; n < 4; ++n) {
                const int d = 16 * n + c;
                const int s = ((ck * 4 + g) ^ (d & 7)) * 8;
                bf16x8 vh = *(const bf16x8*)(VHI + d * 64 + s);
                bf16x8 vl = *(const bf16x8*)(VLO + d * 64 + s);
                o_acc[0][n] = MFMA16(pah[0], vh, o_acc[0][n]);
                o_acc[1][n] = MFMA16(pah[1], vh, o_acc[1][n]);
                o_acc[0][n] = MFMA16(pal[0], vh, o_acc[0][n]);
                o_acc[1][n] = MFMA16(pal[1], vh, o_acc[1][n]);
                o_acc[0][n] = MFMA16(pah[0], vl, o_acc[0][n]);
                o_acc[1][n] = MFMA16(pah[1], vl, o_acc[1][n]);
            }
            __builtin_amdgcn_s_setprio(0);
        }
    }

    // ---- normalize + store O in CHUNK format over proj Q bytes (GEMM2 A) ----
    #pragma unroll
    for (int qs = 0; qs < 2; ++qs) {
        const float inv = 1.f / l_run[qs];
        #pragma unroll
        for (int r = 0; r < 4; ++r) {
            const float invr = __shfl(inv, 20 * g + r);
            unsigned short* op = (unsigned short*)(projB
                + (rowbase + qbase + 32 * w + 16 * qs + 4 * g + r) * (size_t)12288
                + 8192);
            #pragma unroll
            for (int n = 0; n < 4; ++n) {
                const float v = o_acc[qs][n][r] * invr;
                const int col = h * HD_ + 16 * n + c;
                const int kc2 = col >> 5;
                const int j   = col & 31;
                const unsigned short hi = f2bf(v);
                op[kc2 * 64 + j]      = hi;
                op[kc2 * 64 + 32 + j] = f2bf(v - bf2f(hi));
            }
        }
    }
}

extern "C" void kernel_launch(void* const* d_in, const int* in_sizes, int n_in,
                              void* d_out, int out_size, void* d_ws, size_t ws_size,
                              hipStream_t stream) {
    const float* x      = (const float*)d_in[0];
    const float* w_in   = (const float*)d_in[1];
    const float* w_gate = (const float*)d_in[2];
    const float* b_gate = (const float*)d_in[3];
    const float* amp    = (const float*)d_in[4];
    const float* shp    = (const float*)d_in[5];
    const float* off    = (const float*)d_in[6];
    float* outp = (float*)d_out;

    // workspace (peak 60.25 MB) + d_out double-duty:
    //   d_out (16 MB):  x chunk format (convert_x) until GEMM1 done; final
    //                   output written by GEMM2's fused-gate epilogue.
    //   [0,48M):        proj (4096 rows x 12288 B). GEMM1 writes V^T planes
    //                   (bytes [0,4096), plane-row i at rows 2i hi/2i+1 lo),
    //                   K hi/lo planes ([4096,8192)), Q fp32 ([8192,12288)).
    //                   attn overwrites Q bytes with O chunks.
    //   [48M,+256K):    bias_rel (log2-scaled)
    //   [48.25M,+12M):  w_inT chunks -> wgT interleaved chunks after GEMM1
    char* ws = (char*)d_ws;
    float*    proj     = (float*)ws;
    float*    bias_rel = (float*)(ws + 50331648);
    unsigned short* wT = (unsigned short*)(ws + 50331648 + 262144);
    unsigned short* xc = (unsigned short*)d_out;

    tisa_bias_kernel<<<(H_ * REL_ + 255) / 256, 256, 0, stream>>>(amp, shp, off, bias_rel);
    convert_x_kernel<<<2048, 256, 0, stream>>>(x, xc);
    convert_wT_kernel<false><<<dim3(D3_ / 64, D_ / 64), 256, 0, stream>>>(w_in, wT, D_, D3_);
    gemm_split_kernel<1><<<dim3(D3_ / 128, 32), 256, 0, stream>>>(
        xc, wT, nullptr, proj, D3_, D_, 4096, D3_);
    convert_wT_kernel<true><<<dim3(D2_ / 64, D_ / 64), 256, 0, stream>>>(w_gate, wT, D_, D2_);
    attn_mfma_kernel<<<512, 256, 0, stream>>>(proj, ws, bias_rel);
    gemm_split_kernel<2><<<dim3(D2_ / 128, 32), 256, 0, stream>>>(
        ws + 8192, wT, b_gate, outp, D2_, D_, 12288, D_);
}

// Round 20
// 272.045 us; speedup vs baseline: 1.0406x; 1.0406x over previous
//
#include <hip/hip_runtime.h>
#include <math.h>

#define B_   2
#define S_   2048
#define D_   1024
#define H_   16
#define K_   21
#define HD_  64
#define D3_  3072
#define D2_  2048
#define REL_ 4095  // 2S-1
#define LOG2E 1.44269504f

typedef __attribute__((ext_vector_type(8))) short bf16x8;
typedef __attribute__((ext_vector_type(8))) unsigned short u16x8;
typedef __attribute__((ext_vector_type(4))) float f32x4;

#define MFMA16(a, b, c) __builtin_amdgcn_mfma_f32_16x16x32_bf16((a), (b), (c), 0, 0, 0)

__device__ __forceinline__ unsigned short f2bf(float f) {
    union { float f; unsigned u; } v; v.f = f;
    return (unsigned short)((v.u + 0x7fffu + ((v.u >> 16) & 1u)) >> 16);
}
__device__ __forceinline__ float bf2f(unsigned short h) {
    union { unsigned u; float f; } v; v.u = ((unsigned)h) << 16;
    return v.f;
}
__device__ __forceinline__ float asf(unsigned u) {
    union { unsigned u; float f; } v; v.u = u; return v.f;
}
// raw HW exp2: D = 2^S0 (what __expf uses internally, minus the mul)
__device__ __forceinline__ float fexp2(float x) {
    float r;
    asm("v_exp_f32 %0, %1" : "=v"(r) : "v"(x));
    return r;
}
// HW pair convert: dst[15:0]=bf16(a) (RTNE), dst[31:16]=bf16(b)
__device__ __forceinline__ unsigned cvtpk(float a, float b) {
    unsigned r;
    asm("v_cvt_pk_bf16_f32 %0, %1, %2" : "=v"(r) : "v"(a), "v"(b));
    return r;
}
// split 8 f32 -> hi bf16x8 + lo bf16x8 (bit-identical to f2bf-based split)
#define SPLIT8(f, ph, pl)                                                      \
    {                                                                          \
        _Pragma("unroll")                                                      \
        for (int _t = 0; _t < 4; ++_t) ph.u[_t] = cvtpk(f[2*_t], f[2*_t+1]);   \
        _Pragma("unroll")                                                      \
        for (int _t = 0; _t < 4; ++_t) {                                       \
            float _h0 = asf(ph.u[_t] << 16);                                   \
            float _h1 = asf(ph.u[_t] & 0xffff0000u);                           \
            pl.u[_t] = cvtpk(f[2*_t] - _h0, f[2*_t+1] - _h1);                  \
        }                                                                      \
    }

// async global->LDS, 16B per lane; LDS dest = wave-uniform base + lane*16
__device__ __forceinline__ void gload16(const void* g, void* l) {
    __builtin_amdgcn_global_load_lds(
        (const __attribute__((address_space(1))) unsigned int*)g,
        (__attribute__((address_space(3))) unsigned int*)l, 16, 0, 0);
}

// ---------------- TISA relative-position bias table (pre-scaled by log2e) ----
__global__ void tisa_bias_kernel(const float* __restrict__ amp,
                                 const float* __restrict__ shp,
                                 const float* __restrict__ off,
                                 float* __restrict__ bias_rel) {
    int idx = blockIdx.x * blockDim.x + threadIdx.x;
    if (idx >= H_ * REL_) return;
    int h = idx / REL_;
    int r = idx - h * REL_;
    float rel = (float)(r - (S_ - 1));
    float acc = 0.f;
    #pragma unroll
    for (int k = 0; k < K_; ++k) {
        float d = rel - off[h * K_ + k];
        acc = fmaf(amp[h * K_ + k], expf(-fabsf(shp[h * K_ + k]) * d * d), acc);
    }
    bias_rel[idx] = acc * LOG2E;   // attention works in log2 domain
}

// ---------------- x -> chunk format (no transpose) ----------------
// out[row][kc][64] u16: hi[32]|lo[32], row stride 2048 u16 (4096 B)
__global__ __launch_bounds__(256) void convert_x_kernel(
    const float* __restrict__ in, unsigned short* __restrict__ out)
{
    const int t   = blockIdx.x * 256 + threadIdx.x;  // 0..524287
    const int row = t >> 7;
    const int c8  = (t & 127) * 8;
    const float* src = in + (size_t)row * D_ + c8;
    float v[8];
    *(float4*)&v[0] = *(const float4*)src;
    *(float4*)&v[4] = *(const float4*)(src + 4);
    unsigned short hi[8], lo[8];
    #pragma unroll
    for (int i = 0; i < 8; ++i) {
        hi[i] = f2bf(v[i]);
        lo[i] = f2bf(v[i] - bf2f(hi[i]));
    }
    const int kc = c8 >> 5;
    const int j0 = c8 & 31;
    unsigned short* op = out + (size_t)row * 2048 + kc * 64;
    *(u16x8*)&op[j0]      = *(u16x8*)&hi[0];
    *(u16x8*)&op[32 + j0] = *(u16x8*)&lo[0];
}

// ---------------- weight transpose + bf16 split (chunk format) ----------------
// in: Kd x N fp32 row-major.  out: [Ndest][Kd/32][64] ushort, chunk = hi[32]|lo[32].
// PERM: dest col = 2*src (src<1024) or 2*(src-1024)+1 (gate interleave).
template<bool PERM>
__global__ __launch_bounds__(256) void convert_wT_kernel(
    const float* __restrict__ in, unsigned short* __restrict__ out, int Kd, int N)
{
    __shared__ float t[64][65];
    const int tid = threadIdx.x;
    const int k0 = blockIdx.y * 64;
    const int n0 = blockIdx.x * 64;
    {
        const int r  = tid >> 2;
        const int cq = (tid & 3) * 16;
        #pragma unroll
        for (int e = 0; e < 4; ++e) {
            float4 v = *(const float4*)&in[(size_t)(k0 + r) * N + n0 + cq + 4 * e];
            t[r][cq + 4 * e + 0] = v.x;
            t[r][cq + 4 * e + 1] = v.y;
            t[r][cq + 4 * e + 2] = v.z;
            t[r][cq + 4 * e + 3] = v.w;
        }
    }
    __syncthreads();
    {
        const int n  = tid >> 2;
        const int ks = (tid & 3) * 16;
        const int nkc = Kd >> 5;
        unsigned short hi[16], lo[16];
        #pragma unroll
        for (int i = 0; i < 16; ++i) {
            float v = t[ks + i][n];
            hi[i] = f2bf(v);
            lo[i] = f2bf(v - bf2f(hi[i]));
        }
        const int kg = k0 + ks;
        const int kc = kg >> 5;
        const int j0 = kg & 31;
        const int nsrc = n0 + n;
        const int dc = PERM ? ((nsrc < 1024) ? 2 * nsrc : 2 * (nsrc - 1024) + 1) : nsrc;
        unsigned short* op = out + (size_t)dc * (nkc * 64) + kc * 64;
        *(u16x8*)&op[j0]          = *(u16x8*)&hi[0];
        *(u16x8*)&op[j0 + 8]      = *(u16x8*)&hi[8];
        *(u16x8*)&op[32 + j0]     = *(u16x8*)&lo[0];
        *(u16x8*)&op[32 + j0 + 8] = *(u16x8*)&lo[8];
    }
}

// ---------------- bf16x3 split-precision MFMA GEMM, 128x128 tile ----------
// 4 waves (2x2), each 64x64 output (4x4 16x16 frags, 48 MFMA/kc, 16 b128
// reads -> 341 B/MFMA).  A pre-split chunk rows at byte stride lda; both
// sides staged via gload16.  2-phase double-buffer with counted vmcnt(8).
// EPI=1 (proj): n0<1024 -> K hi/lo planes into row bytes [4096,8192);
//               n0<2048 -> V^T hi/lo planes into rows 2i/2i+1 bytes [0,4096);
//               else    -> Q fp32 at C[row*ldc+col].
// EPI=2 (gate): interleaved cols; out = a*sigmoid(g) written to C (ldc=1024).
template<int EPI>
__global__ __launch_bounds__(256) void gemm_split_kernel(
    const void* Ap, const unsigned short* __restrict__ Bt,
    const float* __restrict__ bias, float* C,
    int N, int Kd, int lda, int ldc)
{
    __shared__ unsigned short Al[2][128 * 64];  // 2 x 16 KB
    __shared__ unsigned short Bl[2][128 * 64];  // 2 x 16 KB
    const int tid  = threadIdx.x;
    const int w    = tid >> 6;
    const int lane = tid & 63;
    const int c    = lane & 15;
    const int g    = lane >> 4;
    const int m0   = blockIdx.y * 128;
    const int n0   = blockIdx.x * 128;
    const int wrow = (w >> 1) * 64;
    const int wcol = (w & 1) * 64;
    const int nkc  = Kd >> 5;

    f32x4 acc[4][4];
    #pragma unroll
    for (int i = 0; i < 4; ++i)
        #pragma unroll
        for (int j = 0; j < 4; ++j) acc[i][j] = (f32x4){0.f, 0.f, 0.f, 0.f};

    const int srowB  = w * 8 + (lane >> 3);
    const int sslotB = lane & 7;

#define STAGE_AB(buf, kcv)                                                    \
    {                                                                         \
        _Pragma("unroll")                                                     \
        for (int i = 0; i < 4; ++i) {                                         \
            const int row = w * 32 + i * 8 + (lane >> 3);                     \
            const char* src = (const char*)Ap + (size_t)(m0 + row) * lda      \
                            + (kcv) * 128 + (((lane & 7) ^ (row & 7)) << 4);  \
            gload16(src, (char*)Al[buf] + w * 4096 + i * 1024);               \
        }                                                                     \
        _Pragma("unroll")                                                     \
        for (int i = 0; i < 4; ++i) {                                         \
            const int n = i * 32 + srowB;                                     \
            const unsigned short* src = Bt                                    \
                + ((size_t)(n0 + n) * nkc + (kcv)) * 64                       \
                + ((sslotB ^ (n & 7)) << 3);                                  \
            gload16(src, (char*)Bl[buf] + i * 4096 + w * 1024);               \
        }                                                                     \
    }

    STAGE_AB(0, 0);   // 8 loads in flight for buf0
    int cur = 0;

    for (int kc = 0; kc < nkc; ++kc) {
        if (kc + 1 < nkc) {
            STAGE_AB(cur ^ 1, kc + 1);  // +8 loads; 16 in flight
            asm volatile("s_waitcnt vmcnt(8)" ::: "memory");  // prev 8 done
        } else {
            asm volatile("s_waitcnt vmcnt(0)" ::: "memory");
        }
        __builtin_amdgcn_s_barrier();       // publish all waves' buf[cur]
        __builtin_amdgcn_sched_barrier(0);

        bf16x8 ah[4], al[4], bh[4], bl[4];
        #pragma unroll
        for (int f = 0; f < 4; ++f) {
            const int m = wrow + f * 16 + c;
            const char* rp = (const char*)Al[cur] + m * 128;
            ah[f] = *(const bf16x8*)(rp + (((g + 0) ^ (m & 7)) << 4));
            al[f] = *(const bf16x8*)(rp + (((g + 4) ^ (m & 7)) << 4));
            const int n = wcol + f * 16 + c;
            const char* rq = (const char*)Bl[cur] + n * 128;
            bh[f] = *(const bf16x8*)(rq + (((g + 0) ^ (n & 7)) << 4));
            bl[f] = *(const bf16x8*)(rq + (((g + 4) ^ (n & 7)) << 4));
        }
        #pragma unroll
        for (int mf = 0; mf < 4; ++mf)
            #pragma unroll
            for (int nf = 0; nf < 4; ++nf) {
                acc[mf][nf] = MFMA16(ah[mf], bh[nf], acc[mf][nf]);
                acc[mf][nf] = MFMA16(al[mf], bh[nf], acc[mf][nf]);
                acc[mf][nf] = MFMA16(ah[mf], bl[nf], acc[mf][nf]);
            }
        // WAR: all waves done reading buf[cur] before next iter stages into it
        asm volatile("s_waitcnt lgkmcnt(0)" ::: "memory");
        __builtin_amdgcn_s_barrier();
        cur ^= 1;
    }
#undef STAGE_AB

    // ---------------- epilogues ----------------
    if (EPI == 1) {
        if (n0 < 1024) {  // K hi/lo planes into proj row bytes [4096,8192)
            #pragma unroll
            for (int mf = 0; mf < 4; ++mf)
                #pragma unroll
                for (int r = 0; r < 4; ++r) {
                    const int row = m0 + wrow + mf * 16 + g * 4 + r;
                    char* rowB = (char*)C + (size_t)row * 12288;
                    #pragma unroll
                    for (int nf = 0; nf < 4; ++nf) {
                        const int col = n0 + wcol + nf * 16 + c;
                        const float val = acc[mf][nf][r];
                        const unsigned short hi = f2bf(val);
                        *(unsigned short*)(rowB + 4096 + 2 * col) = hi;
                        *(unsigned short*)(rowB + 6144 + 2 * col) = f2bf(val - bf2f(hi));
                    }
                }
        } else if (n0 < 2048) {  // V^T planes: i=b*1024+d -> rows 2i/2i+1 bytes [0,4096)
            #pragma unroll
            for (int mf = 0; mf < 4; ++mf) {
                const int row0 = m0 + wrow + mf * 16 + g * 4;
                const int s2 = (row0 & 2047) * 2;
                const size_t ibase = (size_t)(row0 >> 11) * 1024;
                #pragma unroll
                for (int nf = 0; nf < 4; ++nf) {
                    const int d = n0 - 1024 + wcol + nf * 16 + c;
                    ushort4 hv, lv;
                    {
                        float v0 = acc[mf][nf][0], v1 = acc[mf][nf][1];
                        float v2 = acc[mf][nf][2], v3 = acc[mf][nf][3];
                        hv.x = f2bf(v0); lv.x = f2bf(v0 - bf2f(hv.x));
                        hv.y = f2bf(v1); lv.y = f2bf(v1 - bf2f(hv.y));
                        hv.z = f2bf(v2); lv.z = f2bf(v2 - bf2f(hv.z));
                        hv.w = f2bf(v3); lv.w = f2bf(v3 - bf2f(hv.w));
                    }
                    char* base = (char*)C + (ibase + d) * (size_t)24576 + s2;
                    *(ushort4*)base           = hv;
                    *(ushort4*)(base + 12288) = lv;
                }
            }
        } else {  // Q fp32
            #pragma unroll
            for (int mf = 0; mf < 4; ++mf)
                #pragma unroll
                for (int r = 0; r < 4; ++r) {
                    const int row = m0 + wrow + mf * 16 + g * 4 + r;
                    float* cp = &C[(size_t)row * ldc + n0 + wcol + c];
                    #pragma unroll
                    for (int nf = 0; nf < 4; ++nf)
                        cp[nf * 16] = acc[mf][nf][r];
                }
        }
    } else {  // EPI == 2: fused gate. even col jc=2t holds a_t, odd holds g_t.
        float bgs[4];
        #pragma unroll
        for (int nf = 0; nf < 4; ++nf) {
            const int jc = n0 + wcol + nf * 16 + c;
            bgs[nf] = bias[(jc & 1) ? (1024 + (jc >> 1)) : (jc >> 1)];
        }
        #pragma unroll
        for (int mf = 0; mf < 4; ++mf)
            #pragma unroll
            for (int r = 0; r < 4; ++r) {
                const int row = m0 + wrow + mf * 16 + g * 4 + r;
                #pragma unroll
                for (int nf = 0; nf < 4; ++nf) {
                    const int jc = n0 + wcol + nf * 16 + c;
                    const float val = acc[mf][nf][r] + bgs[nf];
                    const float part = __shfl_xor(val, 1);
                    if (!(c & 1))
                        C[(size_t)row * ldc + (jc >> 1)] = val / (1.f + __expf(-part));
                }
            }
    }
}

// ---------------- MFMA flash attention: 128q blocks, 8 waves, sliced P ----
// (round-14/18 best-known version: 60 VGPR, 38% occupancy, MfmaUtil 35% =
// this structure's LDS-BW cap; r19's 2-q-set variant regressed via VGPR/occ)
__global__ __launch_bounds__(512) void attn_mfma_kernel(
    const float* projf, char* projB, const float* __restrict__ bias_rel)
{
    __shared__ unsigned short KHI[4096], KLO[4096], VHI[4096], VLO[4096];  // 8 KB each
    __shared__ unsigned short PHI[4096], PLO[4096];  // 128q x 32k slice, 8 KB each
    __shared__ float bias_s[192];

    const int tid  = threadIdx.x;
    const int w    = tid >> 6;    // 0..7
    const int lane = tid & 63;
    const int c    = lane & 15;
    const int g    = lane >> 4;
    // XCD-aware decode: 16 q-blocks of one (h,b) panel land on one XCD
    const int bid  = blockIdx.x;
    const int xcd  = bid & 7;
    const int slot = bid >> 3;            // 0..63
    const int qt   = slot & 15;
    const int p    = (slot >> 4) * 8 + xcd;  // 0..31
    const int h    = p >> 1;
    const int b    = p & 1;
    const int qbase = qt * 128;
    const size_t rowbase = (size_t)b * S_;
    const int q    = 16 * w + c;          // block-local q row
    // P-slice slot swizzle: covers all 8 (parity,16B-slot) bank-quads evenly
    const int psw  = (q & 3) ^ ((q >> 2) & 1);

    // Q fragments from fp32 Q columns (retired before first barrier)
    bf16x8 Qhi[2], Qlo[2];
    {
        const float* qp = projf + (rowbase + qbase + q) * D3_ + 2 * D_ + h * HD_;
        #pragma unroll
        for (int ck = 0; ck < 2; ++ck) {
            float q8[8];
            *(float4*)&q8[0] = *(const float4*)(qp + ck * 32 + g * 8);
            *(float4*)&q8[4] = *(const float4*)(qp + ck * 32 + g * 8 + 4);
            union { unsigned u[4]; bf16x8 v; } ph, pl;
            const float* f = q8;
            SPLIT8(f, ph, pl);
            Qhi[ck] = ph.v;
            Qlo[ck] = pl.v;
        }
    }

    f32x4 o_acc[4];
    #pragma unroll
    for (int n = 0; n < 4; ++n) o_acc[n] = (f32x4){0.f, 0.f, 0.f, 0.f};
    float m_run = -INFINITY;  // running max (log2 domain)
    float l_run = 0.f;

    // ---- reg-staged prefetch (T14): 1 uint4 per buffer per thread ----
    const int srow = tid >> 3;            // 0..63
    const int gsl  = (tid & 7) ^ (srow & 7);
    uint4 rkh, rkl, rvh, rvl;
    float breg = 0.f;

#define LOADKV(ktv)                                                            \
    {                                                                          \
        const int kbase_ = (ktv) * 64;                                         \
        const char* ks = projB + (rowbase + kbase_ + srow) * (size_t)12288     \
                       + 4096 + h * 128 + gsl * 16;                            \
        rkh = *(const uint4*)ks;  rkl = *(const uint4*)(ks + 2048);            \
        const char* vs = projB + (size_t)(b * 1024 + h * HD_ + srow) * 24576   \
                       + (size_t)kbase_ * 2 + gsl * 16;                        \
        rvh = *(const uint4*)vs;  rvl = *(const uint4*)(vs + 12288);           \
        if (tid < 191)                                                         \
            breg = bias_rel[h * REL_ + kbase_ - qbase + 1920 + tid];           \
    }

    LOADKV(0);

    for (int kt = 0; kt < S_ / 64; ++kt) {
        __syncthreads();  // previous tile's LDS reads complete
        {
            const int d = srow * 128 + (tid & 7) * 16;
            *(uint4*)((char*)KHI + d) = rkh;
            *(uint4*)((char*)KLO + d) = rkl;
            *(uint4*)((char*)VHI + d) = rvh;
            *(uint4*)((char*)VLO + d) = rvl;
            if (tid < 191) bias_s[tid] = breg;
        }
        if (kt + 1 < S_ / 64) LOADKV(kt + 1);
        __syncthreads();  // staging visible

        // ---- S^T = K Q (bf16x3): sf[f][r] = P[k=16f+4g+r][q] ----
        f32x4 sf[4];
        __builtin_amdgcn_s_setprio(1);
        #pragma unroll
        for (int f = 0; f < 4; ++f) {
            f32x4 acc = (f32x4){0.f, 0.f, 0.f, 0.f};
            const int krow = f * 16 + c;
            const unsigned short* kbp = KHI + krow * 64;
            const unsigned short* klp = KLO + krow * 64;
            #pragma unroll
            for (int ck = 0; ck < 2; ++ck) {
                const int s = ((ck * 4 + g) ^ (krow & 7)) * 8;
                bf16x8 kh  = *(const bf16x8*)(kbp + s);
                bf16x8 kl8 = *(const bf16x8*)(klp + s);
                acc = MFMA16(kh, Qhi[ck], acc);
                acc = MFMA16(kl8, Qhi[ck], acc);
                acc = MFMA16(kh, Qlo[ck], acc);
            }
            sf[f] = acc;
        }
        __builtin_amdgcn_s_setprio(0);

        // ---- scale + TISA bias (log2 domain): rel = k - q ----
        #pragma unroll
        for (int f = 0; f < 4; ++f) {
            const int tb = 16 * f + 4 * g - q + 127;
            #pragma unroll
            for (int r = 0; r < 4; ++r)
                sf[f][r] = fmaf(sf[f][r], 0.125f * LOG2E, bias_s[tb + r]);
        }

        // ---- lane-local online softmax, defer-max (THR=8*log2e), v_exp ----
        float pm[4];
        #pragma unroll
        for (int f = 0; f < 4; ++f)
            pm[f] = fmaxf(fmaxf(sf[f][0], sf[f][1]), fmaxf(sf[f][2], sf[f][3]));
        float mt = fmaxf(fmaxf(pm[0], pm[1]), fmaxf(pm[2], pm[3]));
        mt = fmaxf(mt, __shfl_xor(mt, 16));
        mt = fmaxf(mt, __shfl_xor(mt, 32));
        if (!__all(mt <= m_run + 11.5415603f)) {
            const float mn = fmaxf(m_run, mt);
            const float sc = fexp2(m_run - mn);
            l_run *= sc;
            m_run = mn;
            #pragma unroll
            for (int r = 0; r < 4; ++r) {
                const float scr = __shfl(sc, 20 * g + r);
                #pragma unroll
                for (int n = 0; n < 4; ++n) o_acc[n][r] *= scr;
            }
        }
        float ps[4];
        #pragma unroll
        for (int f = 0; f < 4; ++f) {
            #pragma unroll
            for (int r = 0; r < 4; ++r)
                sf[f][r] = fexp2(sf[f][r] - m_run);
            ps[f] = (sf[f][0] + sf[f][1]) + (sf[f][2] + sf[f][3]);
        }
        float rs = (ps[0] + ps[1]) + (ps[2] + ps[3]);
        rs += __shfl_xor(rs, 16);
        rs += __shfl_xor(rs, 32);
        l_run += rs;

        // ---- O += P V per 32-k slice: split-on-write P, pure-b128 reads ----
        #pragma unroll
        for (int ck = 0; ck < 2; ++ck) {
            #pragma unroll
            for (int f2 = 0; f2 < 2; ++f2) {
                const int f = 2 * ck + f2;
                const unsigned uh0 = cvtpk(sf[f][0], sf[f][1]);
                const unsigned uh1 = cvtpk(sf[f][2], sf[f][3]);
                const float r0 = sf[f][0] - asf(uh0 << 16);
                const float r1 = sf[f][1] - asf(uh0 & 0xffff0000u);
                const float r2 = sf[f][2] - asf(uh1 << 16);
                const float r3 = sf[f][3] - asf(uh1 & 0xffff0000u);
                const unsigned ul0 = cvtpk(r0, r1);
                const unsigned ul1 = cvtpk(r2, r3);
                const int byte = q * 64
                    + ((((2 * f2 + (g >> 1)) ^ psw) << 4) + ((g & 1) << 3));
                uint2 vh2; vh2.x = uh0; vh2.y = uh1;
                uint2 vl2; vl2.x = ul0; vl2.y = ul1;
                *(uint2*)((char*)PHI + byte) = vh2;
                *(uint2*)((char*)PLO + byte) = vl2;
            }
            asm volatile("s_waitcnt lgkmcnt(0)" ::: "memory");
            const int rbyte = q * 64 + ((g ^ psw) << 4);
            bf16x8 pah = *(const bf16x8*)((char*)PHI + rbyte);
            bf16x8 pal = *(const bf16x8*)((char*)PLO + rbyte);
            __builtin_amdgcn_s_setprio(1);
            #pragma unroll
            for (int n = 0; n < 4; ++n) {
                const int d = 16 * n + c;
                const int s = ((ck * 4 + g) ^ (d & 7)) * 8;
                bf16x8 vh = *(const bf16x8*)(VHI + d * 64 + s);
                bf16x8 vl = *(const bf16x8*)(VLO + d * 64 + s);
                o_acc[n] = MFMA16(pah, vh, o_acc[n]);
                o_acc[n] = MFMA16(pal, vh, o_acc[n]);
                o_acc[n] = MFMA16(pah, vl, o_acc[n]);
            }
            __builtin_amdgcn_s_setprio(0);
        }
    }
#undef LOADKV

    // ---- normalize + store O in CHUNK format over proj Q bytes (GEMM2 A) ----
    const float inv = 1.f / l_run;
    #pragma unroll
    for (int r = 0; r < 4; ++r) {
        const float invr = __shfl(inv, 20 * g + r);
        unsigned short* op = (unsigned short*)(projB
            + (rowbase + qbase + 16 * w + 4 * g + r) * (size_t)12288 + 8192);
        #pragma unroll
        for (int n = 0; n < 4; ++n) {
            const float v = o_acc[n][r] * invr;
            const int col = h * HD_ + 16 * n + c;
            const int kc2 = col >> 5;
            const int j   = col & 31;
            const unsigned short hi = f2bf(v);
            op[kc2 * 64 + j]      = hi;
            op[kc2 * 64 + 32 + j] = f2bf(v - bf2f(hi));
        }
    }
}

extern "C" void kernel_launch(void* const* d_in, const int* in_sizes, int n_in,
                              void* d_out, int out_size, void* d_ws, size_t ws_size,
                              hipStream_t stream) {
    const float* x      = (const float*)d_in[0];
    const float* w_in   = (const float*)d_in[1];
    const float* w_gate = (const float*)d_in[2];
    const float* b_gate = (const float*)d_in[3];
    const float* amp    = (const float*)d_in[4];
    const float* shp    = (const float*)d_in[5];
    const float* off    = (const float*)d_in[6];
    float* outp = (float*)d_out;

    // workspace (peak 60.25 MB) + d_out double-duty:
    //   d_out (16 MB):  x chunk format (convert_x) until GEMM1 done; final
    //                   output written by GEMM2's fused-gate epilogue.
    //   [0,48M):        proj (4096 rows x 12288 B). GEMM1 writes V^T planes
    //                   (bytes [0,4096), plane-row i at rows 2i hi/2i+1 lo),
    //                   K hi/lo planes ([4096,8192)), Q fp32 ([8192,12288)).
    //                   attn overwrites Q bytes with O chunks.
    //   [48M,+256K):    bias_rel (log2-scaled)
    //   [48.25M,+12M):  w_inT chunks -> wgT interleaved chunks after GEMM1
    char* ws = (char*)d_ws;
    float*    proj     = (float*)ws;
    float*    bias_rel = (float*)(ws + 50331648);
    unsigned short* wT = (unsigned short*)(ws + 50331648 + 262144);
    unsigned short* xc = (unsigned short*)d_out;

    tisa_bias_kernel<<<(H_ * REL_ + 255) / 256, 256, 0, stream>>>(amp, shp, off, bias_rel);
    convert_x_kernel<<<2048, 256, 0, stream>>>(x, xc);
    convert_wT_kernel<false><<<dim3(D3_ / 64, D_ / 64), 256, 0, stream>>>(w_in, wT, D_, D3_);
    gemm_split_kernel<1><<<dim3(D3_ / 128, 32), 256, 0, stream>>>(
        xc, wT, nullptr, proj, D3_, D_, 4096, D3_);
    convert_wT_kernel<true><<<dim3(D2_ / 64, D_ / 64), 256, 0, stream>>>(w_gate, wT, D_, D2_);
    attn_mfma_kernel<<<512, 512, 0, stream>>>(proj, ws, bias_rel);
    gemm_split_kernel<2><<<dim3(D2_ / 128, 32), 256, 0, stream>>>(
        ws + 8192, wT, b_gate, outp, D2_, D_, 12288, D_);
}